// Round 11
// baseline (117.694 us; speedup 1.0000x reference)
//
#include <hip/hip_runtime.h>
#include <hip/hip_bf16.h>
#include <math.h>

// Problem constants
#define N_TOK 16384
#define I_DIM 128
#define O_DIM 128
#define G_DIM 16
// GEMM tiling
#define BN 64                       // n-rows per block (grid 256 = 1 block/CU)
#define CI 4                        // i-values per K-chunk
#define KC (CI * G_DIM * 2)         // 128 k per chunk
#define NCHUNK (I_DIM / CI)         // 32 chunks
#define A_STRIDE 136                // bf16 elems per LDS A row (272 B)
#define ABUF (BN * A_STRIDE)        // 8704 elems = 17408 B per A buffer
#define BSLICE 4096                 // bf16 elems per wave's 8 KB B slice
#define BBUF (4 * BSLICE)           // 16384 elems = 32 KB per B buffer
#define C_STRIDE 132                // floats per LDS C row (epilogue)
#define PK_STRIDE 68                // floats per LDS row in pack kernel (272 B)

typedef __bf16 bf16x8 __attribute__((ext_vector_type(8)));
typedef float  f32x4  __attribute__((ext_vector_type(4)));

// global -> LDS async DMA, 16 B per lane (m97 pattern; dest = base + lane*16)
#define GLOAD_LDS16(g, l) __builtin_amdgcn_global_load_lds( \
    (const __attribute__((address_space(1))) void*)(g),     \
    (__attribute__((address_space(3))) void*)(l), 16, 0, 0)

// ---------------------------------------------------------------------------
// Pack cos/sin amplitudes (O,I,G) fp32 -> bf16 Bp in MFMA-FRAGMENT order:
//   element (frag*64 + lane)*8 + j, frag = ((c*4 + cg)*4 + ks)*2 + ot,
//   lane = quad*16 + row16, o = cg*32+ot*16+row16, i = c*4+ks,
//   g = quad*4 + (j>>1), s = j&1 (0=cos 1=sin).
// GRID = 128 (32 c x 4 cg). LDS transpose: coalesced reads AND writes.
// Verified passing in r9/r10.
// ---------------------------------------------------------------------------
__global__ __launch_bounds__(256) void fkan_pack_b(
    const float* __restrict__ cosA, const float* __restrict__ sinA,
    __bf16* __restrict__ Bp)
{
    __shared__ __align__(16) float cosL[32 * PK_STRIDE];
    __shared__ __align__(16) float sinL[32 * PK_STRIDE];
    const int b = blockIdx.x;        // 0..127 = c*4 + cg
    const int t = threadIdx.x;
    const int c = b >> 2, cg = b & 3;

    {
        const int o_l = t >> 3;      // 0..31
        const int k   = t & 7;       // float4 slot base
        const float* srcc = cosA + ((size_t)(cg * 32 + o_l) * I_DIM + c * 4) * G_DIM;
        const float* srcs = sinA + ((size_t)(cg * 32 + o_l) * I_DIM + c * 4) * G_DIM;
#pragma unroll
        for (int h = 0; h < 2; ++h) {
            int col = (k + 8 * h) * 4;
            *(float4*)(cosL + o_l * PK_STRIDE + col) = *(const float4*)(srcc + col);
            *(float4*)(sinL + o_l * PK_STRIDE + col) = *(const float4*)(srcs + col);
        }
    }
    __syncthreads();

#pragma unroll
    for (int h = 0; h < 2; ++h) {
        int gi    = t + 256 * h;     // 0..511 group within this block's slice
        int fl    = gi >> 6;         // frag local = ks*2 + ot
        int lane  = gi & 63;
        int ks    = fl >> 1, ot = fl & 1;
        int row16 = lane & 15, quad = lane >> 4;
        int orow  = ot * 16 + row16;
        int colb  = ks * 16 + quad * 4;
        bf16x8 v;
#pragma unroll
        for (int j = 0; j < 4; ++j) {
            v[2 * j]     = (__bf16)cosL[orow * PK_STRIDE + colb + j];
            v[2 * j + 1] = (__bf16)sinL[orow * PK_STRIDE + colb + j];
        }
        *(bf16x8*)(Bp + ((size_t)b * 512 + gi) * 8) = v;
    }
}

// ---------------------------------------------------------------------------
// Fused: features (cos/sin of x*freq) -> bf16 MFMA GEMM -> bias -> LayerNorm
// Grid: 256 blocks x 256 threads (4 waves) = 1 block/CU. Block 64n x 128o;
// wave tile 64n x 32o (wave = cg; 4 m-tiles x 2 o-tiles of 16x16x32).
// B path (r11): global_load_lds DMA into a 2 x 32 KB LDS double-buffer.
// The DMA has NO destination VGPR -> the compiler cannot sink it to its use
// (r4 evidence: VGPR_Count=64 proved register prefetch was being defeated).
// Each wave DMAs only its own 8 KB slice and is its only reader -> B needs
// no barrier; completion is consumed via a counted s_waitcnt vmcnt(9).
// Every phase issues exactly 1 x-load + 8 DMAs (tail-clamped) so the vmcnt
// census is uniform. A: LDS double-buffer, 1 thread = 1 16-harmonic chain.
// ONE raw barrier per chunk (A only), lgkm-only drain.
// ---------------------------------------------------------------------------
__global__ __launch_bounds__(256) void fkan_main(
    const float* __restrict__ x,
    const __bf16* __restrict__ Bp,
    const float* __restrict__ bias,
    const float* __restrict__ gamma,
    const float* __restrict__ beta,
    float* __restrict__ out)
{
    // LDS: 2 x A (17408 B) + 2 x B (32768 B) = 100352 B -> 1 block/CU.
    // Epilogue C tile (64 x 132 f32 = 33792 B) reuses the A region (34816 B).
    __shared__ __align__(16) __bf16 smem[2 * ABUF + 2 * BBUF];
    __bf16* A0 = smem;
    __bf16* A1 = smem + ABUF;
    __bf16* B0 = smem + 2 * ABUF;
    __bf16* B1 = B0 + BBUF;

    const int t     = threadIdx.x;
    const int lane  = t & 63;
    const int cg    = t >> 6;          // wave = o-column group (0..3)
    const int row16 = lane & 15;
    const int quad  = lane >> 4;
    const int n0    = blockIdx.x * BN;

    // feature-staging role: thread t -> (n = t/4, il = t%4), full 16-chain
    const int fn  = t >> 2;
    const int fil = t & 3;

    f32x4 acc[4][2];
#pragma unroll
    for (int mt = 0; mt < 4; ++mt)
#pragma unroll
        for (int ot = 0; ot < 2; ++ot)
            acc[mt][ot] = (f32x4){0.f, 0.f, 0.f, 0.f};

    auto ld_x = [&](int c) -> float {
        return x[(size_t)(n0 + fn) * I_DIM + c * CI + fil];
    };

    // ---- async DMA of this wave's 8 KB B slice for chunk c -> LDS buffer ----
    auto dma_b = [&](int c, __bf16* Bw) {
        const __bf16* src = Bp + (size_t)(c * 4 + cg) * 4096 + lane * 8;
        __bf16* dst = Bw + cg * BSLICE + lane * 8;
#pragma unroll
        for (int j = 0; j < 8; ++j)
            GLOAD_LDS16(src + j * 512, dst + j * 512);
    };

    // ---- compute 32 bf16 features for (fn, i = c*4+fil), write to LDS ----
    auto stage_a = [&](float xv, __bf16* Ab) {
        float s1, c1;
        __sincosf(xv, &s1, &c1);
        __align__(16) __bf16 feat[32];
        feat[0] = (__bf16)c1;
        feat[1] = (__bf16)s1;
        float ck = c1, sk = s1;
#pragma unroll
        for (int g = 1; g < 16; ++g) {
            float cn = ck * c1 - sk * s1;   // cos((g+1)x)
            float sn = sk * c1 + ck * s1;   // sin((g+1)x)
            feat[2 * g]     = (__bf16)cn;
            feat[2 * g + 1] = (__bf16)sn;
            ck = cn; sk = sn;
        }
        bf16x8* dst = (bf16x8*)(Ab + fn * A_STRIDE + fil * 32);
        const bf16x8* srcv = (const bf16x8*)feat;
#pragma unroll
        for (int j = 0; j < 4; ++j) dst[j] = srcv[j];
    };

    // ---- one K-chunk phase: DMA c+1, prefetch x(c+2), stage A(c+1), MFMA c ----
    auto phase = [&](int c, const __bf16* Ar, __bf16* Aw,
                     const __bf16* Br, __bf16* Bw, float xs, float& xn) {
        int cx = (c + 2 < NCHUNK) ? c + 2 : NCHUNK - 1;   // tail-clamped: census
        int cb = (c + 1 < NCHUNK) ? c + 1 : NCHUNK - 1;   // stays 1 x + 8 DMA
        xn = ld_x(cx);                    // 1 vmem (register relay)
        dma_b(cb, Bw);                    // 8 vmem -> LDS (fire-and-forget)
        stage_a(xs, Aw);                  // VALU chain + 4 ds_write (other buffer)

        // chunk c's 8 DMAs (issued last phase) are the 10th-newest and older:
        asm volatile("s_waitcnt vmcnt(9)" ::: "memory");
        __builtin_amdgcn_s_setprio(1);
#pragma unroll
        for (int ks = 0; ks < 4; ++ks) {
            bf16x8 b0 = *(const bf16x8*)(Br + cg * BSLICE + (ks * 2 + 0) * 512 + lane * 8);
            bf16x8 b1 = *(const bf16x8*)(Br + cg * BSLICE + (ks * 2 + 1) * 512 + lane * 8);
            bf16x8 a[4];
#pragma unroll
            for (int mt = 0; mt < 4; ++mt)
                a[mt] = *(const bf16x8*)(Ar + (mt * 16 + row16) * A_STRIDE
                                         + ks * 32 + quad * 8);
#pragma unroll
            for (int mt = 0; mt < 4; ++mt) {
                acc[mt][0] = __builtin_amdgcn_mfma_f32_16x16x32_bf16(a[mt], b0, acc[mt][0], 0, 0, 0);
                acc[mt][1] = __builtin_amdgcn_mfma_f32_16x16x32_bf16(a[mt], b1, acc[mt][1], 0, 0, 0);
            }
        }
        __builtin_amdgcn_s_setprio(0);

        asm volatile("s_waitcnt lgkmcnt(0)" ::: "memory");  // A writes visible, reads retired
        __builtin_amdgcn_sched_barrier(0);
        __builtin_amdgcn_s_barrier();        // barrier is for A only; DMAs span it
    };

    // ---- prologue: x(0), x(1), DMA chunk 0, stage A chunk 0 ----
    float xA = ld_x(0);
    float xB = ld_x(1);
    dma_b(0, B0);
    stage_a(xA, A0);
    asm volatile("s_waitcnt lgkmcnt(0)" ::: "memory");
    __builtin_amdgcn_s_barrier();

    for (int cc = 0; cc < NCHUNK / 2; ++cc) {
        phase(2 * cc,     A0, A1, B0, B1, xB, xA);   // stages chunk 2cc+1 (x = xB)
        phase(2 * cc + 1, A1, A0, B1, B0, xA, xB);   // stages chunk 2cc+2 (x = xA)
    }

    // ---- epilogue: acc -> LDS C, bias + LayerNorm over O=128, store fp32 ----
    // C/D layout: col(o within 16) = lane&15, row(m within 16) = quad*4 + reg
    float* Cs = (float*)smem;          // A region only; tail DMAs land in B region
#pragma unroll
    for (int mt = 0; mt < 4; ++mt)
#pragma unroll
        for (int ot = 0; ot < 2; ++ot)
#pragma unroll
            for (int r = 0; r < 4; ++r)
                Cs[(mt * 16 + quad * 4 + r) * C_STRIDE + cg * 32 + ot * 16 + row16] =
                    acc[mt][ot][r];
    __syncthreads();

    {
        const int r  = t >> 2;         // row within block (0..63)
        const int qt = t & 3;          // quarter of the O dim
        const float* crow = Cs + r * C_STRIDE + qt * 32;
        float vals[32];
        float sum = 0.f, sumsq = 0.f;
#pragma unroll
        for (int j4 = 0; j4 < 8; ++j4) {
            f32x4 v4 = *(const f32x4*)(crow + 4 * j4);
#pragma unroll
            for (int e = 0; e < 4; ++e) {
                float v = v4[e] + bias[qt * 32 + 4 * j4 + e];
                vals[4 * j4 + e] = v;
                sum += v;
                sumsq += v * v;
            }
        }
        // combine the 4 threads of this row (same wave, lanes differ in bits 0-1)
        sum   += __shfl_xor(sum, 1);   sum   += __shfl_xor(sum, 2);
        sumsq += __shfl_xor(sumsq, 1); sumsq += __shfl_xor(sumsq, 2);
        float mu   = sum * (1.0f / O_DIM);
        float var  = sumsq * (1.0f / O_DIM) - mu * mu;
        float rstd = rsqrtf(var + 1e-5f);

        float* orow = out + (size_t)(n0 + r) * O_DIM + qt * 32;
#pragma unroll
        for (int j4 = 0; j4 < 8; ++j4) {
            float4 o4;
            o4.x = (vals[4*j4+0] - mu) * rstd * gamma[qt*32 + 4*j4+0] + beta[qt*32 + 4*j4+0];
            o4.y = (vals[4*j4+1] - mu) * rstd * gamma[qt*32 + 4*j4+1] + beta[qt*32 + 4*j4+1];
            o4.z = (vals[4*j4+2] - mu) * rstd * gamma[qt*32 + 4*j4+2] + beta[qt*32 + 4*j4+2];
            o4.w = (vals[4*j4+3] - mu) * rstd * gamma[qt*32 + 4*j4+3] + beta[qt*32 + 4*j4+3];
            *(float4*)(orow + 4 * j4) = o4;
        }
    }
}

extern "C" void kernel_launch(void* const* d_in, const int* in_sizes, int n_in,
                              void* d_out, int out_size, void* d_ws, size_t ws_size,
                              hipStream_t stream) {
    const float* x     = (const float*)d_in[0];
    const float* cosA  = (const float*)d_in[1];
    const float* sinA  = (const float*)d_in[2];
    const float* bias  = (const float*)d_in[3];
    const float* gamma = (const float*)d_in[4];
    const float* beta  = (const float*)d_in[5];
    float* out = (float*)d_out;

    __bf16* Bp = (__bf16*)d_ws;   // 1 MB: fragment-packed bf16 amplitudes

    // GRID = 128: one block per (c, cg) slice of the fragment-packed layout.
    fkan_pack_b<<<dim3(128), dim3(256), 0, stream>>>(cosA, sinA, Bp);
    fkan_main<<<dim3(N_TOK / BN), dim3(256), 0, stream>>>(x, Bp, bias, gamma, beta, out);
}

// Round 12
// 98.564 us; speedup vs baseline: 1.1941x; 1.1941x over previous
//
#include <hip/hip_runtime.h>
#include <hip/hip_bf16.h>
#include <math.h>

// Problem constants
#define N_TOK 16384
#define I_DIM 128
#define O_DIM 128
#define G_DIM 16
// GEMM tiling
#define BN 32                       // n-rows per block
#define CI 8                        // i-values per K-chunk
#define KC (CI * G_DIM * 2)         // 256 k per chunk
#define NCHUNK (I_DIM / CI)         // 16 chunks -> 16 barriers
#define KSTEPS (KC / 32)            // 8 MFMA k-steps per chunk
#define A_STRIDE 264                // bf16 elems per LDS A row (528 B = 33 granules)
#define ABUF (BN * A_STRIDE)        // 8448 elems = 16896 B per A buffer
#define C_STRIDE 132                // floats per LDS C row (epilogue)
#define PK_STRIDE 68                // floats per LDS row in pack kernel (272 B)

typedef __bf16 bf16x8 __attribute__((ext_vector_type(8)));
typedef float  f32x4  __attribute__((ext_vector_type(4)));

// ---------------------------------------------------------------------------
// Pack cos/sin amplitudes (O,I,G) fp32 -> bf16 Bp in MFMA-FRAGMENT order:
//   element (frag*64 + lane)*8 + j, frag = ((cO*4 + cg)*4 + ks4)*2 + ot,
//   lane = quad*16 + row16, o = cg*32+ot*16+row16, i = cO*4+ks4,
//   g = quad*4 + (j>>1), s = j&1 (0=cos 1=sin).   (cO = CI=4-granular chunk)
// GRID = 128 (32 cO x 4 cg). LDS transpose: coalesced reads AND writes.
// Verified passing in r9/r10.
// ---------------------------------------------------------------------------
__global__ __launch_bounds__(256) void fkan_pack_b(
    const float* __restrict__ cosA, const float* __restrict__ sinA,
    __bf16* __restrict__ Bp)
{
    __shared__ __align__(16) float cosL[32 * PK_STRIDE];
    __shared__ __align__(16) float sinL[32 * PK_STRIDE];
    const int b = blockIdx.x;        // 0..127 = cO*4 + cg
    const int t = threadIdx.x;
    const int c = b >> 2, cg = b & 3;

    // ---- stage: 32 o-rows x 64 floats (i_local*16 + g) of each panel ----
    {
        const int o_l = t >> 3;      // 0..31
        const int k   = t & 7;       // float4 slot base
        const float* srcc = cosA + ((size_t)(cg * 32 + o_l) * I_DIM + c * 4) * G_DIM;
        const float* srcs = sinA + ((size_t)(cg * 32 + o_l) * I_DIM + c * 4) * G_DIM;
#pragma unroll
        for (int h = 0; h < 2; ++h) {
            int col = (k + 8 * h) * 4;
            *(float4*)(cosL + o_l * PK_STRIDE + col) = *(const float4*)(srcc + col);
            *(float4*)(sinL + o_l * PK_STRIDE + col) = *(const float4*)(srcs + col);
        }
    }
    __syncthreads();

    // ---- emit: 2 contiguous bf16x8 groups per thread (512 per block) ----
#pragma unroll
    for (int h = 0; h < 2; ++h) {
        int gi    = t + 256 * h;     // 0..511 group within this block's slice
        int fl    = gi >> 6;         // frag local = ks4*2 + ot
        int lane  = gi & 63;
        int ks    = fl >> 1, ot = fl & 1;
        int row16 = lane & 15, quad = lane >> 4;
        int orow  = ot * 16 + row16;
        int colb  = ks * 16 + quad * 4;
        bf16x8 v;
#pragma unroll
        for (int j = 0; j < 4; ++j) {
            v[2 * j]     = (__bf16)cosL[orow * PK_STRIDE + colb + j];
            v[2 * j + 1] = (__bf16)sinL[orow * PK_STRIDE + colb + j];
        }
        *(bf16x8*)(Bp + ((size_t)b * 512 + gi) * 8) = v;   // frag*64+lane = b*512+gi
    }
}

// ---------------------------------------------------------------------------
// Fused: features (cos/sin of x*freq) -> bf16 MFMA GEMM -> bias -> LayerNorm
// Grid: 512 blocks x 256 threads (4 waves) = 2 independent blocks per CU.
// Block tile 32n x 128o; wave tile 32n x 32o (wave = cg; 2x2 of 16x16x32).
// CI=8 -> 16 phases of 32 MFMA each.
// r12 CHANGE (only one): __sincosf -> __sinf/__cosf. HIP's __sincosf is the
// PRECISE ocml sincos (~50+ serial instrs, table range-reduction) -- it has
// been on the per-phase critical path since the round-0 baseline and explains
// the occupancy/structure-invariant ~2600 cyc/phase residual (r4/r6/r9/r10
// nulls; r11's 1:1 serial-work slowdown). Natives = v_sin/v_cos, ~4 instr.
// Accuracy: native err ~1e-5, x15 recurrence -> 1.5e-4 << bf16 quantization.
// B: fragment-packed coalesced global loads, register double-buffered.
// A: features double-buffered in LDS; 1 thread = 1 (row,i) 16-harmonic chain.
// x: register relay prefetched a chunk ahead.
// ONE raw barrier per chunk, lgkm-only drain (B loads span barriers).
// ---------------------------------------------------------------------------
__global__ __launch_bounds__(256, 2) void fkan_main(
    const float* __restrict__ x,
    const __bf16* __restrict__ Bp,
    const float* __restrict__ bias,
    const float* __restrict__ gamma,
    const float* __restrict__ beta,
    float* __restrict__ out)
{
    // LDS: 2 x A buffer (32 x 264 bf16 = 16896 B each) = 33792 B -> 2 blocks/CU.
    // Epilogue C tile (32 x 132 f32 = 16896 B) reuses the same region.
    __shared__ __align__(16) __bf16 smem[2 * ABUF];
    __bf16* A0 = smem;
    __bf16* A1 = smem + ABUF;

    const int t     = threadIdx.x;
    const int lane  = t & 63;
    const int cg    = t >> 6;          // wave = o-column group (0..3)
    const int row16 = lane & 15;
    const int quad  = lane >> 4;
    const int n0    = blockIdx.x * BN;

    // feature-staging role: 1 thread = 1 (row, i-within-chunk) full chain.
    const int srow  = t >> 3;          // 0..31
    const int sil   = t & 7;           // 0..7

    f32x4 acc[2][2];
#pragma unroll
    for (int mt = 0; mt < 2; ++mt)
#pragma unroll
        for (int ot = 0; ot < 2; ++ot)
            acc[mt][ot] = (f32x4){0.f, 0.f, 0.f, 0.f};

    bf16x8 bA[2][KSTEPS], bB[2][KSTEPS];   // [ot][ks] register double-buffer

    auto ld_x = [&](int c) -> float {
        return x[(size_t)(n0 + srow) * I_DIM + c * CI + sil];
    };

    // ---- fragment-packed coalesced B load: 16 x dwordx4 per wave per chunk.
    // CI=8 kstep ks maps to pack's CI=4 chunk cO = c*2 + (ks>>2), kstep ks&3.
    auto ld_b = [&](int c, bf16x8 (&b)[2][KSTEPS]) {
#pragma unroll
        for (int ks = 0; ks < KSTEPS; ++ks) {
            int cO = c * 2 + (ks >> 2);
            const bf16x8* base = (const bf16x8*)Bp
                + (((size_t)(cO * 4 + cg) * 8) + (size_t)(ks & 3) * 2) * 64 + lane;
            b[0][ks] = base[0];
            b[1][ks] = base[64];
        }
    };

    // ---- compute 32 bf16 features (16 harmonics) for (srow, c*8+sil) -> LDS ----
    auto stage_a = [&](float xv, __bf16* Ab) {
        // r12: NATIVE sin/cos (v_sin_f32/v_cos_f32 path), not precise ocml sincos
        float s1 = __sinf(xv);
        float c1 = __cosf(xv);
        __align__(16) __bf16 feat[32];
        feat[0] = (__bf16)c1;
        feat[1] = (__bf16)s1;
        float ck = c1, sk = s1;
#pragma unroll
        for (int g = 1; g < 16; ++g) {
            float cn = ck * c1 - sk * s1;   // cos((g+1)x)
            float sn = sk * c1 + ck * s1;   // sin((g+1)x)
            feat[2 * g]     = (__bf16)cn;
            feat[2 * g + 1] = (__bf16)sn;
            ck = cn; sk = sn;
        }
        bf16x8* dst = (bf16x8*)(Ab + srow * A_STRIDE + sil * 32);
        const bf16x8* srcv = (const bf16x8*)feat;
#pragma unroll
        for (int j = 0; j < 4; ++j) dst[j] = srcv[j];
    };

    // ---- one K-chunk phase: prefetch c+1 (B regs, A LDS, x scalar), MFMA c ----
    auto phase = [&](int c, const __bf16* Ar, __bf16* Aw,
                     bf16x8 (&bcur)[2][KSTEPS], bf16x8 (&bnext)[2][KSTEPS],
                     float xs, float& xn) {
        const bool pf = (c + 1 < NCHUNK);
        if (pf) ld_b(c + 1, bnext);          // coalesced global loads, in flight
        if (c + 2 < NCHUNK) xn = ld_x(c + 2);
        if (pf) stage_a(xs, Aw);             // VALU chain + 4 ds_write (other buffer)

        __builtin_amdgcn_s_setprio(1);
#pragma unroll
        for (int ks = 0; ks < KSTEPS; ++ks) {
            bf16x8 a0 = *(const bf16x8*)(Ar + (row16)      * A_STRIDE + ks * 32 + quad * 8);
            bf16x8 a1 = *(const bf16x8*)(Ar + (16 + row16) * A_STRIDE + ks * 32 + quad * 8);
            acc[0][0] = __builtin_amdgcn_mfma_f32_16x16x32_bf16(a0, bcur[0][ks], acc[0][0], 0, 0, 0);
            acc[0][1] = __builtin_amdgcn_mfma_f32_16x16x32_bf16(a0, bcur[1][ks], acc[0][1], 0, 0, 0);
            acc[1][0] = __builtin_amdgcn_mfma_f32_16x16x32_bf16(a1, bcur[0][ks], acc[1][0], 0, 0, 0);
            acc[1][1] = __builtin_amdgcn_mfma_f32_16x16x32_bf16(a1, bcur[1][ks], acc[1][1], 0, 0, 0);
        }
        __builtin_amdgcn_s_setprio(0);

        asm volatile("s_waitcnt lgkmcnt(0)" ::: "memory");  // A writes visible, reads retired
        __builtin_amdgcn_sched_barrier(0);
        __builtin_amdgcn_s_barrier();        // vmcnt NOT drained: B prefetch spans barrier
    };

    // ---- prologue: stage chunk 0 (the only exposed latency) ----
    float xA = ld_x(0);
    float xB;
    ld_b(0, bA);
    stage_a(xA, A0);
    xB = ld_x(1);
    asm volatile("s_waitcnt lgkmcnt(0)" ::: "memory");
    __builtin_amdgcn_s_barrier();

    for (int cc = 0; cc < NCHUNK / 2; ++cc) {
        phase(2 * cc,     A0, A1, bA, bB, xB, xA);   // stages chunk 2cc+1 (x = xB)
        phase(2 * cc + 1, A1, A0, bB, bA, xA, xB);   // stages chunk 2cc+2 (x = xA)
    }

    // ---- epilogue: acc -> LDS C, bias + LayerNorm over O=128, store fp32 ----
    // C/D layout: col(o within 16) = lane&15, row(m within 16) = quad*4 + reg
    float* Cs = (float*)smem;          // safe: last barrier retired all A-buffer ops
#pragma unroll
    for (int mt = 0; mt < 2; ++mt)
#pragma unroll
        for (int ot = 0; ot < 2; ++ot)
#pragma unroll
            for (int r = 0; r < 4; ++r)
                Cs[(mt * 16 + quad * 4 + r) * C_STRIDE
                   + cg * 32 + ot * 16 + row16] = acc[mt][ot][r];
    __syncthreads();

    {
        const int r  = t >> 3;         // row within block (0..31)
        const int oc = t & 7;          // eighth of the O dim (16 cols each)
        const float* crow = Cs + r * C_STRIDE + oc * 16;
        float vals[16];
        float sum = 0.f, sumsq = 0.f;
#pragma unroll
        for (int j4 = 0; j4 < 4; ++j4) {
            f32x4 v4 = *(const f32x4*)(crow + 4 * j4);
#pragma unroll
            for (int e = 0; e < 4; ++e) {
                float v = v4[e] + bias[oc * 16 + 4 * j4 + e];
                vals[4 * j4 + e] = v;
                sum += v;
                sumsq += v * v;
            }
        }
        // combine the 8 threads of this row (adjacent lanes, bits 0-2)
        sum   += __shfl_xor(sum, 1);   sum   += __shfl_xor(sum, 2);   sum   += __shfl_xor(sum, 4);
        sumsq += __shfl_xor(sumsq, 1); sumsq += __shfl_xor(sumsq, 2); sumsq += __shfl_xor(sumsq, 4);
        float mu   = sum * (1.0f / O_DIM);
        float var  = sumsq * (1.0f / O_DIM) - mu * mu;
        float rstd = rsqrtf(var + 1e-5f);

        float* orow = out + (size_t)(n0 + r) * O_DIM + oc * 16;
#pragma unroll
        for (int j4 = 0; j4 < 4; ++j4) {
            float4 o4;
            o4.x = (vals[4*j4+0] - mu) * rstd * gamma[oc*16 + 4*j4+0] + beta[oc*16 + 4*j4+0];
            o4.y = (vals[4*j4+1] - mu) * rstd * gamma[oc*16 + 4*j4+1] + beta[oc*16 + 4*j4+1];
            o4.z = (vals[4*j4+2] - mu) * rstd * gamma[oc*16 + 4*j4+2] + beta[oc*16 + 4*j4+2];
            o4.w = (vals[4*j4+3] - mu) * rstd * gamma[oc*16 + 4*j4+3] + beta[oc*16 + 4*j4+3];
            *(float4*)(orow + 4 * j4) = o4;
        }
    }
}

extern "C" void kernel_launch(void* const* d_in, const int* in_sizes, int n_in,
                              void* d_out, int out_size, void* d_ws, size_t ws_size,
                              hipStream_t stream) {
    const float* x     = (const float*)d_in[0];
    const float* cosA  = (const float*)d_in[1];
    const float* sinA  = (const float*)d_in[2];
    const float* bias  = (const float*)d_in[3];
    const float* gamma = (const float*)d_in[4];
    const float* beta  = (const float*)d_in[5];
    float* out = (float*)d_out;

    __bf16* Bp = (__bf16*)d_ws;   // 1 MB: fragment-packed bf16 amplitudes

    // GRID = 128: one block per (cO, cg) slice of the CI=4-granular pack layout.
    fkan_pack_b<<<dim3(128), dim3(256), 0, stream>>>(cosA, sinA, Bp);
    fkan_main<<<dim3(N_TOK / BN), dim3(256), 0, stream>>>(x, Bp, bias, gamma, beta, out);
}